// Round 4
// baseline (263.530 us; speedup 1.0000x reference)
//
#include <hip/hip_runtime.h>

// Scatter-add via counting-sort + CSR gather (4-edge/iter float4 gather).
// out = A; for each edge e: out[index[e]] += B[e]
// N_NODES=100000, N_EDGES=1250000, D=64, fp32, index int32.

#define D_FEAT 64
#define SCAN_CHUNK 1024   // elements per scan block (256 threads x 4)

// ---------------- fallback (round-1) path ----------------
__global__ void scatter_add_kernel(const int* __restrict__ index,
                                   const float* __restrict__ B,
                                   float* __restrict__ out,
                                   long long total) {
    long long i = (long long)blockIdx.x * blockDim.x + threadIdx.x;
    if (i >= total) return;
    int e = (int)(i >> 6);
    int f = (int)(i & 63);
    int node = index[e];
    atomicAdd(&out[(long long)node * D_FEAT + f], B[i]);
}

// ---------------- utility ----------------
__global__ void zero_kernel4(int4* __restrict__ p, int n4) {
    int i = blockIdx.x * blockDim.x + threadIdx.x;
    if (i < n4) p[i] = make_int4(0, 0, 0, 0);
}
__global__ void zero_tail(int* __restrict__ p, int start, int n) {
    int i = start + blockIdx.x * blockDim.x + threadIdx.x;
    if (i < n) p[i] = 0;
}

// ---------------- CSR build ----------------
__global__ void hist_kernel(const int* __restrict__ index, int* __restrict__ counts,
                            int n_edges) {
    int i = blockIdx.x * blockDim.x + threadIdx.x;
    int stride = gridDim.x * blockDim.x;
    for (; i < n_edges; i += stride)
        atomicAdd(&counts[index[i]], 1);
}

__global__ void scan_blocksums(const int* __restrict__ counts, int* __restrict__ bsums,
                               int n) {
    __shared__ int lds[256];
    int t = threadIdx.x;
    int base = blockIdx.x * SCAN_CHUNK + t * 4;
    int s = 0;
#pragma unroll
    for (int k = 0; k < 4; ++k) {
        int i = base + k;
        if (i < n) s += counts[i];
    }
    lds[t] = s;
    __syncthreads();
    for (int off = 128; off > 0; off >>= 1) {
        if (t < off) lds[t] += lds[t + off];
        __syncthreads();
    }
    if (t == 0) bsums[blockIdx.x] = lds[0];
}

__global__ void scan_bsums(int* __restrict__ bsums, int* __restrict__ total_out, int nb) {
    __shared__ int lds[256];
    int t = threadIdx.x;
    int v = (t < nb) ? bsums[t] : 0;
    lds[t] = v;
    __syncthreads();
    for (int off = 1; off < 256; off <<= 1) {
        int add = (t >= off) ? lds[t - off] : 0;
        __syncthreads();
        lds[t] += add;
        __syncthreads();
    }
    if (t < nb) bsums[t] = lds[t] - v;
    if (t == nb - 1) *total_out = lds[t];
}

__global__ void scan_final(const int* __restrict__ counts, const int* __restrict__ bsums,
                           int* __restrict__ offsets, int* __restrict__ heads, int n) {
    __shared__ int lds[256];
    int t = threadIdx.x;
    int base = blockIdx.x * SCAN_CHUNK + t * 4;
    int v0 = (base + 0 < n) ? counts[base + 0] : 0;
    int v1 = (base + 1 < n) ? counts[base + 1] : 0;
    int v2 = (base + 2 < n) ? counts[base + 2] : 0;
    int v3 = (base + 3 < n) ? counts[base + 3] : 0;
    int tsum = v0 + v1 + v2 + v3;
    lds[t] = tsum;
    __syncthreads();
    for (int off = 1; off < 256; off <<= 1) {
        int add = (t >= off) ? lds[t - off] : 0;
        __syncthreads();
        lds[t] += add;
        __syncthreads();
    }
    int excl = lds[t] - tsum + bsums[blockIdx.x];
    int o0 = excl;
    int o1 = o0 + v0;
    int o2 = o1 + v1;
    int o3 = o2 + v2;
    if (base + 0 < n) { offsets[base + 0] = o0; heads[base + 0] = o0; }
    if (base + 1 < n) { offsets[base + 1] = o1; heads[base + 1] = o1; }
    if (base + 2 < n) { offsets[base + 2] = o2; heads[base + 2] = o2; }
    if (base + 3 < n) { offsets[base + 3] = o3; heads[base + 3] = o3; }
}

__global__ void place_kernel(const int* __restrict__ index, int* __restrict__ heads,
                             int* __restrict__ edge_list, int n_edges) {
    int i = blockIdx.x * blockDim.x + threadIdx.x;
    int stride = gridDim.x * blockDim.x;
    for (; i < n_edges; i += stride) {
        int node = index[i];
        int pos = atomicAdd(&heads[node], 1);
        edge_list[pos] = i;
    }
}

// ---------------- gather-accumulate, 4 edges / wave-iteration ----------------
// wave = node; lane -> (g = lane>>4 edge subgroup, sub = lane&15 feature quad)
__global__ __launch_bounds__(256) void gather4_kernel(
    const int* __restrict__ offsets,
    const int* __restrict__ edge_list,
    const float* __restrict__ A,
    const float* __restrict__ B,
    float* __restrict__ out, int n_nodes)
{
    int wave = (int)((blockIdx.x * (long long)blockDim.x + threadIdx.x) >> 6);
    if (wave >= n_nodes) return;
    int lane = threadIdx.x & 63;
    int g   = lane >> 4;
    int sub = lane & 15;

    int s = offsets[wave];
    int e = offsets[wave + 1];
    int cnt = e - s;
    int nfull = cnt & ~3;

    float4 acc = make_float4(0.f, 0.f, 0.f, 0.f);

    // software-pipelined main loop: 4 edges per iteration, float4 per lane
    if (nfull > 0) {
        int eid = edge_list[s + g];
        for (int it = 0; it < nfull; it += 4) {
            int eid_next = 0;
            if (it + 4 < nfull) eid_next = edge_list[s + it + 4 + g];
            const float4* brow = (const float4*)(B + (long long)eid * D_FEAT);
            float4 b = brow[sub];
            acc.x += b.x; acc.y += b.y; acc.z += b.z; acc.w += b.w;
            eid = eid_next;
        }
    }
    // remainder (0..3 edges): group g handles edge nfull+g
    int rem = cnt - nfull;
    if (g < rem) {
        int eid = edge_list[s + nfull + g];
        const float4* brow = (const float4*)(B + (long long)eid * D_FEAT);
        float4 b = brow[sub];
        acc.x += b.x; acc.y += b.y; acc.z += b.z; acc.w += b.w;
    }

    // butterfly-reduce across the 4 edge subgroups (lane bits 4 and 5)
    acc.x += __shfl_xor(acc.x, 16); acc.y += __shfl_xor(acc.y, 16);
    acc.z += __shfl_xor(acc.z, 16); acc.w += __shfl_xor(acc.w, 16);
    acc.x += __shfl_xor(acc.x, 32); acc.y += __shfl_xor(acc.y, 32);
    acc.z += __shfl_xor(acc.z, 32); acc.w += __shfl_xor(acc.w, 32);

    if (g == 0) {
        const float4* arow = (const float4*)(A + (long long)wave * D_FEAT);
        float4 a = arow[sub];
        float4 r;
        r.x = a.x + acc.x; r.y = a.y + acc.y;
        r.z = a.z + acc.z; r.w = a.w + acc.w;
        ((float4*)(out + (long long)wave * D_FEAT))[sub] = r;
    }
}

extern "C" void kernel_launch(void* const* d_in, const int* in_sizes, int n_in,
                              void* d_out, int out_size, void* d_ws, size_t ws_size,
                              hipStream_t stream) {
    const int*   index = (const int*)d_in[0];   // (N_EDGES,) int32
    const float* A     = (const float*)d_in[1]; // (N_NODES, 64) f32
    const float* B     = (const float*)d_in[2]; // (N_EDGES, 64) f32
    float*       out   = (float*)d_out;         // (N_NODES, 64) f32

    const int n_edges = in_sizes[0];
    const int n_nodes = out_size / D_FEAT;
    const int nblocks_scan = (n_nodes + SCAN_CHUNK - 1) / SCAN_CHUNK;

    size_t need = ((size_t)n_nodes * 2 + (size_t)(n_nodes + 1) +
                   (size_t)nblocks_scan + (size_t)n_edges) * sizeof(int);

    if (ws_size < need || nblocks_scan > 256) {
        hipMemcpyAsync(out, A, (size_t)out_size * sizeof(float),
                       hipMemcpyDeviceToDevice, stream);
        long long total = (long long)n_edges * D_FEAT;
        int block = 256;
        long long grid = (total + block - 1) / block;
        scatter_add_kernel<<<(int)grid, block, 0, stream>>>(index, B, out, total);
        return;
    }

    int* counts    = (int*)d_ws;                    // n_nodes
    int* heads     = counts + n_nodes;              // n_nodes
    int* offsets   = heads + n_nodes;               // n_nodes + 1
    int* bsums     = offsets + (n_nodes + 1);       // nblocks_scan
    int* edge_list = bsums + nblocks_scan;          // n_edges

    // zero counts (custom: rocclr fill kernel is pathologically slow here)
    {
        int n4 = n_nodes >> 2;
        zero_kernel4<<<(n4 + 255) / 256, 256, 0, stream>>>((int4*)counts, n4);
        int tail = n_nodes - (n4 << 2);
        if (tail > 0)
            zero_tail<<<1, 64, 0, stream>>>(counts, n4 << 2, n_nodes);
    }
    {
        int block = 256;
        int grid = min((n_edges + block - 1) / block, 2048);
        hist_kernel<<<grid, block, 0, stream>>>(index, counts, n_edges);
    }
    scan_blocksums<<<nblocks_scan, 256, 0, stream>>>(counts, bsums, n_nodes);
    scan_bsums<<<1, 256, 0, stream>>>(bsums, &offsets[n_nodes], nblocks_scan);
    scan_final<<<nblocks_scan, 256, 0, stream>>>(counts, bsums, offsets, heads, n_nodes);
    {
        int block = 256;
        int grid = min((n_edges + block - 1) / block, 2048);
        place_kernel<<<grid, block, 0, stream>>>(index, heads, edge_list, n_edges);
    }
    {
        long long threads = (long long)n_nodes * 64;
        int block = 256;
        int grid = (int)((threads + block - 1) / block);
        gather4_kernel<<<grid, block, 0, stream>>>(offsets, edge_list, A, B, out, n_nodes);
    }
}

// Round 8
// 244.389 us; speedup vs baseline: 1.0783x; 1.0783x over previous
//
#include <hip/hip_runtime.h>

// Scatter-add via counting-sort + CSR gather. Round-3 structure (known pass)
// with ONE change: int4-vectorized hist/place (bisection of round-6/7 bug).
// out = A; for each edge e: out[index[e]] += B[e]
// N_NODES=100000, N_EDGES=1250000, D=64, fp32, index int32.

#define D_FEAT 64
#define SCAN_CHUNK 1024   // elements per scan block (256 threads x 4)

// ---------------- fallback (round-1) path ----------------
__global__ void scatter_add_kernel(const int* __restrict__ index,
                                   const float* __restrict__ B,
                                   float* __restrict__ out,
                                   long long total) {
    long long i = (long long)blockIdx.x * blockDim.x + threadIdx.x;
    if (i >= total) return;
    int e = (int)(i >> 6);
    int f = (int)(i & 63);
    int node = index[e];
    atomicAdd(&out[(long long)node * D_FEAT + f], B[i]);
}

// ---------------- utility ----------------
__global__ void zero_kernel(int* __restrict__ p, int n) {
    int i = blockIdx.x * blockDim.x + threadIdx.x;
    if (i < n) p[i] = 0;
}

// ---------------- CSR build ----------------
// CHANGED (only change vs round 3): int4 index loads, 4 edges/thread.
__global__ void hist_kernel(const int* __restrict__ index, int* __restrict__ counts,
                            int n) {
    int i = (blockIdx.x * blockDim.x + threadIdx.x) * 4;
    if (i + 3 < n) {
        int4 v = *(const int4*)(index + i);
        atomicAdd(&counts[v.x], 1);
        atomicAdd(&counts[v.y], 1);
        atomicAdd(&counts[v.z], 1);
        atomicAdd(&counts[v.w], 1);
    } else {
        for (int k = i; k < n; ++k) atomicAdd(&counts[index[k]], 1);
    }
}

// Phase A: per-block (1024-element chunk) sums
__global__ void scan_blocksums(const int* __restrict__ counts, int* __restrict__ bsums,
                               int n) {
    __shared__ int lds[256];
    int t = threadIdx.x;
    int base = blockIdx.x * SCAN_CHUNK + t * 4;
    int s = 0;
#pragma unroll
    for (int k = 0; k < 4; ++k) {
        int i = base + k;
        if (i < n) s += counts[i];
    }
    lds[t] = s;
    __syncthreads();
    for (int off = 128; off > 0; off >>= 1) {
        if (t < off) lds[t] += lds[t + off];
        __syncthreads();
    }
    if (t == 0) bsums[blockIdx.x] = lds[0];
}

// Phase B: single block exclusive-scans block sums (nb <= 256)
__global__ void scan_bsums(int* __restrict__ bsums, int* __restrict__ total_out, int nb) {
    __shared__ int lds[256];
    int t = threadIdx.x;
    int v = (t < nb) ? bsums[t] : 0;
    lds[t] = v;
    __syncthreads();
    for (int off = 1; off < 256; off <<= 1) {
        int add = (t >= off) ? lds[t - off] : 0;
        __syncthreads();
        lds[t] += add;
        __syncthreads();
    }
    if (t < nb) bsums[t] = lds[t] - v;        // exclusive prefix
    if (t == nb - 1) *total_out = lds[t];     // offsets[n_nodes]
}

// Phase C: final exclusive scan -> offsets & heads
__global__ void scan_final(const int* __restrict__ counts, const int* __restrict__ bsums,
                           int* __restrict__ offsets, int* __restrict__ heads, int n) {
    __shared__ int lds[256];
    int t = threadIdx.x;
    int base = blockIdx.x * SCAN_CHUNK + t * 4;
    int v0 = (base + 0 < n) ? counts[base + 0] : 0;
    int v1 = (base + 1 < n) ? counts[base + 1] : 0;
    int v2 = (base + 2 < n) ? counts[base + 2] : 0;
    int v3 = (base + 3 < n) ? counts[base + 3] : 0;
    int tsum = v0 + v1 + v2 + v3;
    lds[t] = tsum;
    __syncthreads();
    for (int off = 1; off < 256; off <<= 1) {
        int add = (t >= off) ? lds[t - off] : 0;
        __syncthreads();
        lds[t] += add;
        __syncthreads();
    }
    int excl = lds[t] - tsum + bsums[blockIdx.x];
    int o0 = excl;
    int o1 = o0 + v0;
    int o2 = o1 + v1;
    int o3 = o2 + v2;
    if (base + 0 < n) { offsets[base + 0] = o0; heads[base + 0] = o0; }
    if (base + 1 < n) { offsets[base + 1] = o1; heads[base + 1] = o1; }
    if (base + 2 < n) { offsets[base + 2] = o2; heads[base + 2] = o2; }
    if (base + 3 < n) { offsets[base + 3] = o3; heads[base + 3] = o3; }
}

// CHANGED (only change vs round 3): int4 index loads, 4 edges/thread.
__global__ void place_kernel(const int* __restrict__ index, int* __restrict__ heads,
                             int* __restrict__ edge_list, int n) {
    int i = (blockIdx.x * blockDim.x + threadIdx.x) * 4;
    if (i + 3 < n) {
        int4 v = *(const int4*)(index + i);
        int p0 = atomicAdd(&heads[v.x], 1); edge_list[p0] = i;
        int p1 = atomicAdd(&heads[v.y], 1); edge_list[p1] = i + 1;
        int p2 = atomicAdd(&heads[v.z], 1); edge_list[p2] = i + 2;
        int p3 = atomicAdd(&heads[v.w], 1); edge_list[p3] = i + 3;
    } else {
        for (int k = i; k < n; ++k) {
            int p = atomicAdd(&heads[index[k]], 1);
            edge_list[p] = k;
        }
    }
}

// ---------------- gather-accumulate (round-3 version, proven) ----------------
// one wave per node; lane = feature
__global__ void gather_kernel(const int* __restrict__ offsets,
                              const int* __restrict__ edge_list,
                              const float* __restrict__ A,
                              const float* __restrict__ B,
                              float* __restrict__ out, int n_nodes) {
    int wave = (int)((blockIdx.x * (long long)blockDim.x + threadIdx.x) >> 6);
    int lane = threadIdx.x & 63;
    if (wave >= n_nodes) return;
    int s = __builtin_amdgcn_readfirstlane(offsets[wave]);
    int e = __builtin_amdgcn_readfirstlane(offsets[wave + 1]);
    float acc = A[(long long)wave * D_FEAT + lane];
    int j = s;
    for (; j + 1 < e; j += 2) {
        int e0 = edge_list[j];
        int e1 = edge_list[j + 1];
        float b0 = B[(long long)e0 * D_FEAT + lane];
        float b1 = B[(long long)e1 * D_FEAT + lane];
        acc += b0;
        acc += b1;
    }
    if (j < e) {
        int e0 = edge_list[j];
        acc += B[(long long)e0 * D_FEAT + lane];
    }
    out[(long long)wave * D_FEAT + lane] = acc;
}

extern "C" void kernel_launch(void* const* d_in, const int* in_sizes, int n_in,
                              void* d_out, int out_size, void* d_ws, size_t ws_size,
                              hipStream_t stream) {
    const int*   index = (const int*)d_in[0];   // (N_EDGES,) int32
    const float* A     = (const float*)d_in[1]; // (N_NODES, 64) f32
    const float* B     = (const float*)d_in[2]; // (N_EDGES, 64) f32
    float*       out   = (float*)d_out;         // (N_NODES, 64) f32

    const int n_edges = in_sizes[0];
    const int n_nodes = out_size / D_FEAT;
    const int nblocks_scan = (n_nodes + SCAN_CHUNK - 1) / SCAN_CHUNK;

    size_t need = ((size_t)n_nodes * 2 + (size_t)(n_nodes + 1) +
                   (size_t)nblocks_scan + (size_t)n_edges) * sizeof(int);

    if (ws_size < need || nblocks_scan > 256) {
        hipMemcpyAsync(out, A, (size_t)out_size * sizeof(float),
                       hipMemcpyDeviceToDevice, stream);
        long long total = (long long)n_edges * D_FEAT;
        int block = 256;
        long long grid = (total + block - 1) / block;
        scatter_add_kernel<<<(int)grid, block, 0, stream>>>(index, B, out, total);
        return;
    }

    int* counts    = (int*)d_ws;                    // n_nodes
    int* heads     = counts + n_nodes;              // n_nodes
    int* offsets   = heads + n_nodes;               // n_nodes + 1
    int* bsums     = offsets + (n_nodes + 1);       // nblocks_scan
    int* edge_list = bsums + nblocks_scan;          // n_edges

    // custom zero (hipMemsetAsync's fill kernel measured 186us for 400KB!)
    zero_kernel<<<(n_nodes + 255) / 256, 256, 0, stream>>>(counts, n_nodes);

    {
        int block = 256;
        int nthreads = (n_edges + 3) / 4;
        hist_kernel<<<(nthreads + block - 1) / block, block, 0, stream>>>(index, counts, n_edges);
    }
    scan_blocksums<<<nblocks_scan, 256, 0, stream>>>(counts, bsums, n_nodes);
    scan_bsums<<<1, 256, 0, stream>>>(bsums, &offsets[n_nodes], nblocks_scan);
    scan_final<<<nblocks_scan, 256, 0, stream>>>(counts, bsums, offsets, heads, n_nodes);
    {
        int block = 256;
        int nthreads = (n_edges + 3) / 4;
        place_kernel<<<(nthreads + block - 1) / block, block, 0, stream>>>(index, heads, edge_list, n_edges);
    }
    {
        long long threads = (long long)n_nodes * 64;
        int block = 256;
        int grid = (int)((threads + block - 1) / block);
        gather_kernel<<<grid, block, 0, stream>>>(offsets, edge_list, A, B, out, n_nodes);
    }
}

// Round 9
// 220.495 us; speedup vs baseline: 1.1952x; 1.1084x over previous
//
#include <hip/hip_runtime.h>

// Scatter-add via fixed-capacity bucketing + gather. 3 dispatches.
// out = A; for each edge e: out[index[e]] += B[e]
// N_NODES=100000, N_EDGES=1250000, D=64, fp32, index int32.
// Degree is Poisson(12.5) -> max ~38; CAP=64 with a correct (never-taken in
// practice) atomic overflow path.

#define D_FEAT 64
#define CAP    64

// ---------------- fallback (round-1) path ----------------
__global__ void scatter_add_kernel(const int* __restrict__ index,
                                   const float* __restrict__ B,
                                   float* __restrict__ out,
                                   long long total) {
    long long i = (long long)blockIdx.x * blockDim.x + threadIdx.x;
    if (i >= total) return;
    int e = (int)(i >> 6);
    int f = (int)(i & 63);
    int node = index[e];
    atomicAdd(&out[(long long)node * D_FEAT + f], B[i]);
}

// ---------------- 1) init: out = A (float4), cnt = 0 ----------------
__global__ void init_kernel(const float* __restrict__ A,
                            float* __restrict__ out,
                            int* __restrict__ cnt,
                            int n_out4,      // n_nodes*64/4
                            int n_nodes) {
    int i = blockIdx.x * blockDim.x + threadIdx.x;
    if (i < n_out4) ((float4*)out)[i] = ((const float4*)A)[i];
    if (i < n_nodes) cnt[i] = 0;
}

// ---------------- 2) place: bucket edge ids (int4 index loads) ----------------
__device__ __forceinline__ void place_one(int v, int eid,
                                          int* __restrict__ cnt,
                                          int* __restrict__ slots,
                                          float* __restrict__ out,
                                          const float* __restrict__ B) {
    int pos = atomicAdd(&cnt[v], 1);
    if (pos < CAP) {
        slots[(long long)v * CAP + pos] = eid;
    } else {
        // overflow (statistically never with this data): add row directly.
        const float* br = B + (long long)eid * D_FEAT;
        float* o = out + (long long)v * D_FEAT;
        for (int k = 0; k < D_FEAT; ++k) atomicAdd(&o[k], br[k]);
    }
}

__global__ void place_kernel(const int* __restrict__ index,
                             int* __restrict__ cnt,
                             int* __restrict__ slots,
                             float* __restrict__ out,
                             const float* __restrict__ B,
                             int n) {
    int i = (blockIdx.x * blockDim.x + threadIdx.x) * 4;
    if (i + 3 < n) {
        int4 v = *(const int4*)(index + i);
        place_one(v.x, i + 0, cnt, slots, out, B);
        place_one(v.y, i + 1, cnt, slots, out, B);
        place_one(v.z, i + 2, cnt, slots, out, B);
        place_one(v.w, i + 3, cnt, slots, out, B);
    } else {
        for (int k = i; k < n; ++k)
            place_one(index[k], k, cnt, slots, out, B);
    }
}

// ---------------- 3) gather: one wave per node, out += sum(slot rows) ----------------
__global__ __launch_bounds__(256) void gather_kernel(
    const int* __restrict__ cnt,
    const int* __restrict__ slots,
    const float* __restrict__ B,
    float* __restrict__ out, int n_nodes)
{
    int wave = (int)((blockIdx.x * (long long)blockDim.x + threadIdx.x) >> 6);
    int lane = threadIdx.x & 63;
    if (wave >= n_nodes) return;

    int c = __builtin_amdgcn_readfirstlane(cnt[wave]);
    if (c > CAP) c = CAP;
    const int* sl = slots + (long long)wave * CAP;
    long long oidx = (long long)wave * D_FEAT + lane;
    float base = out[oidx];   // = A (+ overflow contributions)

    float acc = 0.f;
    int j = 0;
    for (; j + 1 < c; j += 2) {
        int e0 = __builtin_amdgcn_readfirstlane(sl[j]);
        int e1 = __builtin_amdgcn_readfirstlane(sl[j + 1]);
        float b0 = B[(long long)e0 * D_FEAT + lane];
        float b1 = B[(long long)e1 * D_FEAT + lane];
        acc += b0;
        acc += b1;
    }
    if (j < c) {
        int e0 = __builtin_amdgcn_readfirstlane(sl[j]);
        acc += B[(long long)e0 * D_FEAT + lane];
    }
    out[oidx] = base + acc;
}

extern "C" void kernel_launch(void* const* d_in, const int* in_sizes, int n_in,
                              void* d_out, int out_size, void* d_ws, size_t ws_size,
                              hipStream_t stream) {
    const int*   index = (const int*)d_in[0];   // (N_EDGES,) int32
    const float* A     = (const float*)d_in[1]; // (N_NODES, 64) f32
    const float* B     = (const float*)d_in[2]; // (N_EDGES, 64) f32
    float*       out   = (float*)d_out;         // (N_NODES, 64) f32

    const int n_edges = in_sizes[0];
    const int n_nodes = out_size / D_FEAT;

    size_t need = ((size_t)n_nodes + (size_t)n_nodes * CAP) * sizeof(int);

    if (ws_size < need) {
        // fallback: memcpy + atomic scatter (known-correct)
        hipMemcpyAsync(out, A, (size_t)out_size * sizeof(float),
                       hipMemcpyDeviceToDevice, stream);
        long long total = (long long)n_edges * D_FEAT;
        int block = 256;
        long long grid = (total + block - 1) / block;
        scatter_add_kernel<<<(int)grid, block, 0, stream>>>(index, B, out, total);
        return;
    }

    int* cnt   = (int*)d_ws;            // n_nodes
    int* slots = cnt + n_nodes;         // n_nodes * CAP

    const int block = 256;

    // 1) init: out = A, cnt = 0
    {
        int n_out4 = out_size / 4;                    // float4 count
        int nthreads = n_out4;                        // >= n_nodes
        init_kernel<<<(nthreads + block - 1) / block, block, 0, stream>>>(
            A, out, cnt, n_out4, n_nodes);
    }
    // 2) place edges into per-node slots (int4 index loads)
    {
        int nthreads = (n_edges + 3) / 4;
        place_kernel<<<(nthreads + block - 1) / block, block, 0, stream>>>(
            index, cnt, slots, out, B, n_edges);
    }
    // 3) gather: out[node] += sum of its B rows
    {
        long long threads = (long long)n_nodes * 64;
        int grid = (int)((threads + block - 1) / block);
        gather_kernel<<<grid, block, 0, stream>>>(cnt, slots, B, out, n_nodes);
    }
}

// Round 10
// 199.113 us; speedup vs baseline: 1.3235x; 1.1074x over previous
//
#include <hip/hip_runtime.h>

// Scatter-add via fixed-capacity bucketing + A-folded gather. 4 dispatches:
// zero -> place -> gather(out = A + sum slots) -> overflow-cleanup (no-op).
// out = A; for each edge e: out[index[e]] += B[e]
// N_NODES=100000, N_EDGES=1250000, D=64, fp32, index int32.
// Degree ~ Poisson(12.5) -> max ~38; CAP=64. Overflow (statistically never)
// goes to a list drained by cleanup_kernel, keeping any-input correctness.

#define D_FEAT 64
#define CAP    64

// ---------------- fallback (round-1) path ----------------
__global__ void scatter_add_kernel(const int* __restrict__ index,
                                   const float* __restrict__ B,
                                   float* __restrict__ out,
                                   long long total) {
    long long i = (long long)blockIdx.x * blockDim.x + threadIdx.x;
    if (i >= total) return;
    int e = (int)(i >> 6);
    int f = (int)(i & 63);
    int node = index[e];
    atomicAdd(&out[(long long)node * D_FEAT + f], B[i]);
}

// ---------------- 1) zero cnt + ovf counter ----------------
__global__ void zero_kernel(int* __restrict__ cnt, int* __restrict__ ovf_cnt,
                            int n_nodes) {
    int i = (blockIdx.x * blockDim.x + threadIdx.x) * 4;
    if (i + 3 < n_nodes) {
        *(int4*)(cnt + i) = make_int4(0, 0, 0, 0);
    } else {
        for (int k = i; k < n_nodes; ++k) cnt[k] = 0;
    }
    if (i == 0) *ovf_cnt = 0;
}

// ---------------- 2) place: bucket edge ids (int4 index loads) ----------------
__device__ __forceinline__ void place_one(int v, int eid,
                                          int* __restrict__ cnt,
                                          int* __restrict__ slots,
                                          int* __restrict__ ovf_cnt,
                                          int* __restrict__ ovf,
                                          int ovf_capacity) {
    int pos = atomicAdd(&cnt[v], 1);
    if (pos < CAP) {
        slots[(long long)v * CAP + pos] = eid;
    } else {
        int op = atomicAdd(ovf_cnt, 1);
        if (op < ovf_capacity) ovf[op] = eid;   // capacity = n_edges: never full
    }
}

__global__ void place_kernel(const int* __restrict__ index,
                             int* __restrict__ cnt,
                             int* __restrict__ slots,
                             int* __restrict__ ovf_cnt,
                             int* __restrict__ ovf,
                             int ovf_capacity,
                             int n) {
    int i = (blockIdx.x * blockDim.x + threadIdx.x) * 4;
    if (i + 3 < n) {
        int4 v = *(const int4*)(index + i);
        place_one(v.x, i + 0, cnt, slots, ovf_cnt, ovf, ovf_capacity);
        place_one(v.y, i + 1, cnt, slots, ovf_cnt, ovf, ovf_capacity);
        place_one(v.z, i + 2, cnt, slots, ovf_cnt, ovf, ovf_capacity);
        place_one(v.w, i + 3, cnt, slots, ovf_cnt, ovf, ovf_capacity);
    } else {
        for (int k = i; k < n; ++k)
            place_one(index[k], k, cnt, slots, ovf_cnt, ovf, ovf_capacity);
    }
}

// ---------------- 3) gather: out = A + sum(slot rows), 4-deep MLP ----------------
__global__ __launch_bounds__(256) void gather_kernel(
    const int* __restrict__ cnt,
    const int* __restrict__ slots,
    const float* __restrict__ A,
    const float* __restrict__ B,
    float* __restrict__ out, int n_nodes)
{
    int wave = (int)((blockIdx.x * (long long)blockDim.x + threadIdx.x) >> 6);
    int lane = threadIdx.x & 63;
    if (wave >= n_nodes) return;

    int c = __builtin_amdgcn_readfirstlane(cnt[wave]);
    if (c > CAP) c = CAP;
    const int* sl = slots + (long long)wave * CAP;
    long long oidx = (long long)wave * D_FEAT + lane;

    float acc = A[oidx];
    int j = 0;
    // 4 independent 256B row reads in flight per wave
    for (; j + 3 < c; j += 4) {
        int e0 = __builtin_amdgcn_readfirstlane(sl[j]);
        int e1 = __builtin_amdgcn_readfirstlane(sl[j + 1]);
        int e2 = __builtin_amdgcn_readfirstlane(sl[j + 2]);
        int e3 = __builtin_amdgcn_readfirstlane(sl[j + 3]);
        float b0 = B[(long long)e0 * D_FEAT + lane];
        float b1 = B[(long long)e1 * D_FEAT + lane];
        float b2 = B[(long long)e2 * D_FEAT + lane];
        float b3 = B[(long long)e3 * D_FEAT + lane];
        acc += b0; acc += b1; acc += b2; acc += b3;
    }
    for (; j < c; ++j) {
        int e0 = __builtin_amdgcn_readfirstlane(sl[j]);
        acc += B[(long long)e0 * D_FEAT + lane];
    }
    out[oidx] = acc;
}

// ---------------- 4) overflow cleanup (no-op when ovf_cnt == 0) ----------------
__global__ void cleanup_kernel(const int* __restrict__ ovf_cnt,
                               const int* __restrict__ ovf,
                               const int* __restrict__ index,
                               const float* __restrict__ B,
                               float* __restrict__ out,
                               int ovf_capacity) {
    int n = *ovf_cnt;
    if (n > ovf_capacity) n = ovf_capacity;
    int nwaves = (gridDim.x * blockDim.x) >> 6;
    int wid = (int)((blockIdx.x * (long long)blockDim.x + threadIdx.x) >> 6);
    int lane = threadIdx.x & 63;
    for (int i = wid; i < n; i += nwaves) {
        int eid = __builtin_amdgcn_readfirstlane(ovf[i]);
        int node = __builtin_amdgcn_readfirstlane(index[eid]);
        atomicAdd(&out[(long long)node * D_FEAT + lane],
                  B[(long long)eid * D_FEAT + lane]);
    }
}

extern "C" void kernel_launch(void* const* d_in, const int* in_sizes, int n_in,
                              void* d_out, int out_size, void* d_ws, size_t ws_size,
                              hipStream_t stream) {
    const int*   index = (const int*)d_in[0];   // (N_EDGES,) int32
    const float* A     = (const float*)d_in[1]; // (N_NODES, 64) f32
    const float* B     = (const float*)d_in[2]; // (N_EDGES, 64) f32
    float*       out   = (float*)d_out;         // (N_NODES, 64) f32

    const int n_edges = in_sizes[0];
    const int n_nodes = out_size / D_FEAT;

    size_t need = ((size_t)n_nodes          // cnt
                   + 1                      // ovf_cnt
                   + (size_t)n_edges        // ovf list
                   + (size_t)n_nodes * CAP  // slots
                  ) * sizeof(int);

    if (ws_size < need) {
        hipMemcpyAsync(out, A, (size_t)out_size * sizeof(float),
                       hipMemcpyDeviceToDevice, stream);
        long long total = (long long)n_edges * D_FEAT;
        int block = 256;
        long long grid = (total + block - 1) / block;
        scatter_add_kernel<<<(int)grid, block, 0, stream>>>(index, B, out, total);
        return;
    }

    int* cnt     = (int*)d_ws;              // n_nodes
    int* ovf_cnt = cnt + n_nodes;           // 1
    int* ovf     = ovf_cnt + 1;             // n_edges
    int* slots   = ovf + n_edges;           // n_nodes * CAP

    const int block = 256;

    // 1) zero cnt + ovf counter
    {
        int nthreads = (n_nodes + 3) / 4;
        zero_kernel<<<(nthreads + block - 1) / block, block, 0, stream>>>(
            cnt, ovf_cnt, n_nodes);
    }
    // 2) place edges into per-node slots
    {
        int nthreads = (n_edges + 3) / 4;
        place_kernel<<<(nthreads + block - 1) / block, block, 0, stream>>>(
            index, cnt, slots, ovf_cnt, ovf, n_edges, n_edges);
    }
    // 3) gather: out = A + sum of bucketed B rows
    {
        long long threads = (long long)n_nodes * 64;
        int grid = (int)((threads + block - 1) / block);
        gather_kernel<<<grid, block, 0, stream>>>(cnt, slots, A, B, out, n_nodes);
    }
    // 4) overflow cleanup (empty in practice; keeps any-input correctness)
    cleanup_kernel<<<512, block, 0, stream>>>(ovf_cnt, ovf, index, B, out, n_edges);
}

// Round 11
// 142.566 us; speedup vs baseline: 1.8485x; 1.3966x over previous
//
#include <hip/hip_runtime.h>

// Scatter-add via fixed-capacity bucketing + A-folded gather.
// Slot row layout (per node, 64 ints = 256 B): [cnt, eid0, eid1, ... eid62]
//   -> place's atomic + write hit the same DRAM row;
//   -> gather reads count + all edge ids in ONE coalesced 256B load.
// out = A; for each edge e: out[index[e]] += B[e]
// N_NODES=100000, N_EDGES=1250000, D=64, fp32, index int32.
// Degree ~ Poisson(12.5) -> max ~38; 63 slots/node. Overflow (statistically
// never) goes to a list drained by cleanup_kernel (any-input correctness).

#define D_FEAT    64
#define ROW_INTS  64   // 1 cnt + 63 eids
#define CAP_SLOTS 63

// ---------------- fallback (round-1) path ----------------
__global__ void scatter_add_kernel(const int* __restrict__ index,
                                   const float* __restrict__ B,
                                   float* __restrict__ out,
                                   long long total) {
    long long i = (long long)blockIdx.x * blockDim.x + threadIdx.x;
    if (i >= total) return;
    int e = (int)(i >> 6);
    int f = (int)(i & 63);
    int node = index[e];
    atomicAdd(&out[(long long)node * D_FEAT + f], B[i]);
}

// ---------------- 1) zero row counts + ovf counter ----------------
__global__ void zero_kernel(int* __restrict__ rows, int* __restrict__ ovf_cnt,
                            int n_nodes) {
    int i = blockIdx.x * blockDim.x + threadIdx.x;
    if (i < n_nodes) rows[(long long)i * ROW_INTS] = 0;
    if (i == 0) *ovf_cnt = 0;
}

// ---------------- 2) place: bucket edge ids (int4 index loads) ----------------
__device__ __forceinline__ void place_one(int v, int eid,
                                          int* __restrict__ rows,
                                          int* __restrict__ ovf_cnt,
                                          int* __restrict__ ovf,
                                          int ovf_capacity) {
    int* row = rows + (long long)v * ROW_INTS;
    int pos = atomicAdd(row, 1);          // word 0 = count
    if (pos < CAP_SLOTS) {
        row[1 + pos] = eid;               // same 256B row as the atomic
    } else {
        int op = atomicAdd(ovf_cnt, 1);
        if (op < ovf_capacity) ovf[op] = eid;
    }
}

__global__ void place_kernel(const int* __restrict__ index,
                             int* __restrict__ rows,
                             int* __restrict__ ovf_cnt,
                             int* __restrict__ ovf,
                             int ovf_capacity,
                             int n) {
    int i = (blockIdx.x * blockDim.x + threadIdx.x) * 4;
    if (i + 3 < n) {
        int4 v = *(const int4*)(index + i);
        place_one(v.x, i + 0, rows, ovf_cnt, ovf, ovf_capacity);
        place_one(v.y, i + 1, rows, ovf_cnt, ovf, ovf_capacity);
        place_one(v.z, i + 2, rows, ovf_cnt, ovf, ovf_capacity);
        place_one(v.w, i + 3, rows, ovf_cnt, ovf, ovf_capacity);
    } else {
        for (int k = i; k < n; ++k)
            place_one(index[k], k, rows, ovf_cnt, ovf, ovf_capacity);
    }
}

// ---------------- 3) gather: out = A + sum(slot rows) ----------------
// One wave per node. ONE coalesced 256B load brings cnt + 63 edge ids into
// the wave (lane j holds word j); __shfl broadcasts (fully convergent wave,
// wave-uniform trip count -> defined behavior). B-row loads 8-deep.
__global__ __launch_bounds__(256) void gather_kernel(
    const int* __restrict__ rows,
    const float* __restrict__ A,
    const float* __restrict__ B,
    float* __restrict__ out, int n_nodes)
{
    int wave = (int)((blockIdx.x * (long long)blockDim.x + threadIdx.x) >> 6);
    int lane = threadIdx.x & 63;
    if (wave >= n_nodes) return;

    // lane j holds rows[wave*64 + j]
    int rowval = rows[(long long)wave * ROW_INTS + lane];
    int c = __shfl(rowval, 0, 64);        // count (wave-uniform)
    if (c > CAP_SLOTS) c = CAP_SLOTS;

    long long oidx = (long long)wave * D_FEAT + lane;
    float acc = A[oidx];

    int j = 0;
    for (; j + 7 < c; j += 8) {
        int e0 = __shfl(rowval, 1 + j + 0, 64);
        int e1 = __shfl(rowval, 1 + j + 1, 64);
        int e2 = __shfl(rowval, 1 + j + 2, 64);
        int e3 = __shfl(rowval, 1 + j + 3, 64);
        int e4 = __shfl(rowval, 1 + j + 4, 64);
        int e5 = __shfl(rowval, 1 + j + 5, 64);
        int e6 = __shfl(rowval, 1 + j + 6, 64);
        int e7 = __shfl(rowval, 1 + j + 7, 64);
        float b0 = B[(long long)e0 * D_FEAT + lane];
        float b1 = B[(long long)e1 * D_FEAT + lane];
        float b2 = B[(long long)e2 * D_FEAT + lane];
        float b3 = B[(long long)e3 * D_FEAT + lane];
        float b4 = B[(long long)e4 * D_FEAT + lane];
        float b5 = B[(long long)e5 * D_FEAT + lane];
        float b6 = B[(long long)e6 * D_FEAT + lane];
        float b7 = B[(long long)e7 * D_FEAT + lane];
        acc += b0; acc += b1; acc += b2; acc += b3;
        acc += b4; acc += b5; acc += b6; acc += b7;
    }
    for (; j + 3 < c; j += 4) {
        int e0 = __shfl(rowval, 1 + j + 0, 64);
        int e1 = __shfl(rowval, 1 + j + 1, 64);
        int e2 = __shfl(rowval, 1 + j + 2, 64);
        int e3 = __shfl(rowval, 1 + j + 3, 64);
        float b0 = B[(long long)e0 * D_FEAT + lane];
        float b1 = B[(long long)e1 * D_FEAT + lane];
        float b2 = B[(long long)e2 * D_FEAT + lane];
        float b3 = B[(long long)e3 * D_FEAT + lane];
        acc += b0; acc += b1; acc += b2; acc += b3;
    }
    for (; j < c; ++j) {
        int e0 = __shfl(rowval, 1 + j, 64);
        acc += B[(long long)e0 * D_FEAT + lane];
    }
    out[oidx] = acc;
}

// ---------------- 4) overflow cleanup (no-op when ovf_cnt == 0) ----------------
__global__ void cleanup_kernel(const int* __restrict__ ovf_cnt,
                               const int* __restrict__ ovf,
                               const int* __restrict__ index,
                               const float* __restrict__ B,
                               float* __restrict__ out,
                               int ovf_capacity) {
    int n = *ovf_cnt;
    if (n > ovf_capacity) n = ovf_capacity;
    int nwaves = (gridDim.x * blockDim.x) >> 6;
    int wid = (int)((blockIdx.x * (long long)blockDim.x + threadIdx.x) >> 6);
    int lane = threadIdx.x & 63;
    for (int i = wid; i < n; i += nwaves) {
        int eid = __builtin_amdgcn_readfirstlane(ovf[i]);
        int node = __builtin_amdgcn_readfirstlane(index[eid]);
        atomicAdd(&out[(long long)node * D_FEAT + lane],
                  B[(long long)eid * D_FEAT + lane]);
    }
}

extern "C" void kernel_launch(void* const* d_in, const int* in_sizes, int n_in,
                              void* d_out, int out_size, void* d_ws, size_t ws_size,
                              hipStream_t stream) {
    const int*   index = (const int*)d_in[0];   // (N_EDGES,) int32
    const float* A     = (const float*)d_in[1]; // (N_NODES, 64) f32
    const float* B     = (const float*)d_in[2]; // (N_EDGES, 64) f32
    float*       out   = (float*)d_out;         // (N_NODES, 64) f32

    const int n_edges = in_sizes[0];
    const int n_nodes = out_size / D_FEAT;

    size_t need = (1                            // ovf_cnt
                   + (size_t)n_edges            // ovf list
                   + (size_t)n_nodes * ROW_INTS // slot rows
                  ) * sizeof(int);

    if (ws_size < need) {
        hipMemcpyAsync(out, A, (size_t)out_size * sizeof(float),
                       hipMemcpyDeviceToDevice, stream);
        long long total = (long long)n_edges * D_FEAT;
        int block = 256;
        long long grid = (total + block - 1) / block;
        scatter_add_kernel<<<(int)grid, block, 0, stream>>>(index, B, out, total);
        return;
    }

    int* ovf_cnt = (int*)d_ws;              // 1
    int* ovf     = ovf_cnt + 1;             // n_edges
    int* rows    = ovf + n_edges;           // n_nodes * ROW_INTS (16B-aligned: 1+n_edges odd... see below)
    // keep rows 256B-aligned for clean row-granule behavior
    rows = (int*)(((uintptr_t)rows + 255) & ~(uintptr_t)255);

    const int block = 256;

    // 1) zero row counts + ovf counter
    zero_kernel<<<(n_nodes + block - 1) / block, block, 0, stream>>>(
        rows, ovf_cnt, n_nodes);
    // 2) place edges into per-node slot rows
    {
        int nthreads = (n_edges + 3) / 4;
        place_kernel<<<(nthreads + block - 1) / block, block, 0, stream>>>(
            index, rows, ovf_cnt, ovf, n_edges, n_edges);
    }
    // 3) gather: out = A + sum of bucketed B rows
    {
        long long threads = (long long)n_nodes * 64;
        int grid = (int)((threads + block - 1) / block);
        gather_kernel<<<grid, block, 0, stream>>>(rows, A, B, out, n_nodes);
    }
    // 4) overflow cleanup (empty in practice; keeps any-input correctness)
    cleanup_kernel<<<512, block, 0, stream>>>(ovf_cnt, ovf, index, B, out, n_edges);
}